// Round 7
// baseline (3140.633 us; speedup 1.0000x reference)
//
#include <hip/hip_runtime.h>

// DSTP-RNN: B=1024, T_ENC=48, 30 decoder steps, H=128, F=17.
// Round 7: BBLK=2, GRID=512 (keeps gate weights L2-resident; round-6's BBLK=1
// overflowed per-XCD L2 -> 2.9GB HBM fetch), NTH=1024 -> 2 blocks x 16 waves
// = 32 waves/CU full occupancy. fp16 weights + v_dot2_f32_f16; pre2/fin/ud
// LDS-resident fp16; all per-step phases remapped for 1024 threads.

#define T_ENC 48
#define H 128
#define FDIM 17
#define BBLK 2
#define NTH 1024
#define GRID 512

// ---- ws HALF offsets ----
#define H_WT1   0          // 19*512*8  = 77824  (e1 gates, [k8][j][8h], K pad 152)
#define H_WT2   77824      // 33*512*8  = 135168 (e2, K pad 264)
#define H_WTD   212992     // 32*512*8  = 131072 (dec, K=256)
#define H_WE1T  344064     // 128*48*2  = 12288  (We1^T pairs, uint idx k2*48+s)
#define H_WE2T  356352     // 12288
#define H_WDT   368640     // 128*128*2 = 32768  (Wd^T pairs, uint idx k2*128+sp)
#define H_UDT   401408     // 64*128*2  = 16384  (Ud^T pairs, uint idx k2*128+h)
// halves end at 417792 -> 835584 B = 208896 floats
// ---- ws FLOAT offsets ----
#define F_B1    208896
#define F_B2    209408
#define F_BD    209920
#define F_MID   210432     // 1024*48*129 fp32 mid [b][t][129]

typedef _Float16 h2_t __attribute__((ext_vector_type(2)));
union H2U { h2_t h; uint u; float f; };

__device__ __forceinline__ h2_t uh(uint v){ H2U x; x.u = v; return x.h; }
__device__ __forceinline__ h2_t fh(float v){ H2U x; x.f = v; return x.h; }
__device__ __forceinline__ uint pack2(float a, float b){
    H2U x; x.h[0] = (_Float16)a; x.h[1] = (_Float16)b; return x.u;
}
__device__ __forceinline__ float dot2f(h2_t a, h2_t b, float c){
#if __has_builtin(__builtin_amdgcn_fdot2)
    return __builtin_amdgcn_fdot2(a, b, c, false);
#else
    return c + (float)a[0]*(float)b[0] + (float)a[1]*(float)b[1];
#endif
}

__device__ __forceinline__ float fast_sigm(float x){
    return __fdividef(1.0f, 1.0f + __expf(-x));
}
__device__ __forceinline__ float fast_tanh(float x){
    float xc = fminf(fmaxf(x, -9.0f), 9.0f);
    float e = __expf(2.0f * xc);
    return __fdividef(e - 1.0f, e + 1.0f);
}

// ---------------- prologue: transpose/fuse weights into ws (fp16) ----------------
__global__ void prep_kernel(const float* __restrict__ We1W, const float* __restrict__ We2W,
                            const float* __restrict__ WdW,  const float* __restrict__ UdW,
                            const float* __restrict__ e1Wih, const float* __restrict__ e1Whh,
                            const float* __restrict__ e1bih, const float* __restrict__ e1bhh,
                            const float* __restrict__ e2Wih, const float* __restrict__ e2Whh,
                            const float* __restrict__ e2bih, const float* __restrict__ e2bhh,
                            const float* __restrict__ dWih,  const float* __restrict__ dWhh,
                            const float* __restrict__ dbih,  const float* __restrict__ dbhh,
                            float* __restrict__ ws)
{
    int idx = blockIdx.x * blockDim.x + threadIdx.x;
    _Float16* wsh = (_Float16*)ws;
    if (idx < 77824) {                       // WT1 [k8][j][8]: k<17 Wih, k<145 Whh, else 0
        int k8 = idx >> 12, r = idx & 4095, j = r >> 3, kq = r & 7, k = k8*8 + kq;
        float v = 0.f;
        if (k < 17) v = e1Wih[j*17 + k]; else if (k < 145) v = e1Whh[j*128 + (k-17)];
        wsh[H_WT1 + idx] = (_Float16)v; return;
    }
    idx -= 77824;
    if (idx < 135168) {                      // WT2: k<129 Wih, k<257 Whh, else 0 (pad 264)
        int k8 = idx >> 12, r = idx & 4095, j = r >> 3, kq = r & 7, k = k8*8 + kq;
        float v = 0.f;
        if (k < 129) v = e2Wih[j*129 + k]; else if (k < 257) v = e2Whh[j*128 + (k-129)];
        wsh[H_WT2 + idx] = (_Float16)v; return;
    }
    idx -= 135168;
    if (idx < 131072) {                      // WTD: k<128 Wih else Whh (K=256)
        int k8 = idx >> 12, r = idx & 4095, j = r >> 3, kq = r & 7, k = k8*8 + kq;
        float v = (k < 128) ? dWih[j*128 + k] : dWhh[j*128 + (k-128)];
        wsh[H_WTD + idx] = (_Float16)v; return;
    }
    idx -= 131072;
    if (idx < 12288) {                       // We1^T pairs
        int pr = idx >> 1, p = idx & 1, k2 = pr / 48, s = pr % 48;
        wsh[H_WE1T + idx] = (_Float16)We1W[s*256 + 2*k2 + p]; return;
    }
    idx -= 12288;
    if (idx < 12288) {
        int pr = idx >> 1, p = idx & 1, k2 = pr / 48, s = pr % 48;
        wsh[H_WE2T + idx] = (_Float16)We2W[s*256 + 2*k2 + p]; return;
    }
    idx -= 12288;
    if (idx < 32768) {                       // Wd^T pairs
        int pr = idx >> 1, p = idx & 1, k2 = pr >> 7, sp = pr & 127;
        wsh[H_WDT + idx] = (_Float16)WdW[sp*256 + 2*k2 + p]; return;
    }
    idx -= 32768;
    if (idx < 16384) {                       // Ud^T pairs
        int pr = idx >> 1, p = idx & 1, k2 = pr >> 7, hh = pr & 127;
        wsh[H_UDT + idx] = (_Float16)UdW[hh*128 + 2*k2 + p]; return;
    }
    idx -= 16384;
    if (idx < 512) { ws[F_B1 + idx] = e1bih[idx] + e1bhh[idx]; return; }
    idx -= 512;
    if (idx < 512) { ws[F_B2 + idx] = e2bih[idx] + e2bhh[idx]; return; }
    idx -= 512;
    if (idx < 512) { ws[F_BD + idx] = dbih[idx] + dbhh[idx]; return; }
}

// gate matmul, 1024 threads = (b, j): g[b][j] = bias[j] + sum_k u[b][k]*W[k][j]
template<int K8>
__device__ __forceinline__ void lstm_gates2w(const float4* __restrict__ W8,
                                             const float* __restrict__ bias,
                                             const uint* __restrict__ u2all,
                                             float* __restrict__ g, int tid)
{
    const int b = tid >> 9, j = tid & 511;
    const uint* u2 = u2all + b*132;
    float a0 = bias[j], a1 = 0.f;
    #pragma unroll
    for (int k8 = 0; k8 + 1 < K8; k8 += 2) {
        float4 w0 = W8[k8*512 + j];
        float4 w1 = W8[(k8+1)*512 + j];
        float4 u0 = *(const float4*)(u2 + 4*k8);
        float4 u1 = *(const float4*)(u2 + 4*k8 + 4);
        a0 = dot2f(fh(w0.x), fh(u0.x), a0); a0 = dot2f(fh(w0.y), fh(u0.y), a0);
        a0 = dot2f(fh(w0.z), fh(u0.z), a0); a0 = dot2f(fh(w0.w), fh(u0.w), a0);
        a1 = dot2f(fh(w1.x), fh(u1.x), a1); a1 = dot2f(fh(w1.y), fh(u1.y), a1);
        a1 = dot2f(fh(w1.z), fh(u1.z), a1); a1 = dot2f(fh(w1.w), fh(u1.w), a1);
    }
    if (K8 & 1) {
        float4 w0 = W8[(K8-1)*512 + j];
        float4 u0 = *(const float4*)(u2 + 4*(K8-1));
        a0 = dot2f(fh(w0.x), fh(u0.x), a0); a0 = dot2f(fh(w0.y), fh(u0.y), a0);
        a0 = dot2f(fh(w0.z), fh(u0.z), a0); a0 = dot2f(fh(w0.w), fh(u0.w), a0);
    }
    g[b*512 + j] = a0 + a1;
}

// softmax over n entries per batch row (2 rows, stride 132), 32 threads per b
__device__ __forceinline__ void softmax2(float* sc, float* at, int n, int tid)
{
    if (tid < 64) {
        int b = tid >> 5, i = tid & 31, base = b*132;
        float m = -1e30f;
        for (int f = i; f < n; f += 32) m = fmaxf(m, sc[base + f]);
        for (int o = 16; o; o >>= 1) m = fmaxf(m, __shfl_xor(m, o, 32));
        float ssum = 0.f;
        for (int f = i; f < n; f += 32) { float p = __expf(sc[base+f] - m); at[base+f] = p; ssum += p; }
        for (int o = 16; o; o >>= 1) ssum += __shfl_xor(ssum, o, 32);
        float inv = __fdividef(1.f, ssum);
        for (int f = i; f < n; f += 32) at[base + f] *= inv;
    }
}

// we[b][s] = [h;c] @ W^T, 768 threads = b(2) x s(48) x kq(8), 16 pairs each
__device__ __forceinline__ void we_phase2w(const uint* __restrict__ W2,
                                           const uint* h2, const uint* c2,
                                           float* sh_we, int tid)
{
    if (tid < 768) {
        int b = tid / 384, r = tid % 384, s = r >> 3, kq = r & 7;
        const uint* st2 = ((kq < 4) ? h2 : c2) + b*64 + (kq & 3)*16;
        const uint* w2  = W2 + (kq*16)*48 + s;
        float acc = 0.f;
        #pragma unroll
        for (int i = 0; i < 16; ++i)
            acc = dot2f(uh(st2[i]), uh(w2[i*48]), acc);
        acc += __shfl_xor(acc, 1);
        acc += __shfl_xor(acc, 2);
        acc += __shfl_xor(acc, 4);
        if (kq == 0) sh_we[b*48 + s] = acc;
    }
}

__global__ __launch_bounds__(NTH, 8)
void dstp_main(const float* __restrict__ ipq,  const float* __restrict__ labp,
               const float* __restrict__ Ue1W, const float* __restrict__ Ue1b,
               const float* __restrict__ Ve1,  const float* __restrict__ Ve1b,
               const float* __restrict__ Ue2W, const float* __restrict__ Ue2b,
               const float* __restrict__ Ve2,  const float* __restrict__ Ve2b,
               const float* __restrict__ Udb,
               const float* __restrict__ Vd,   const float* __restrict__ Vdb,
               const float* __restrict__ regW, const float* __restrict__ regb,
               float* __restrict__ ws, float* __restrict__ out)
{
    extern __shared__ float sm[];
    float* sh_h   = sm;            // 256  h[2][128] fp32
    float* sh_c   = sm + 256;      // 256
    float* sh_we  = sm + 512;      // 96   we[2][48]
    float* sh_sc  = sm + 608;      // 264  scores [2][132]
    float* sh_sc2 = sm + 872;      // 264  score partials
    float* sh_at  = sm + 1136;     // 264  attention
    float* sh_g   = sm + 1400;     // 1024 gates [2][512] / wd partials
    float* sh_x   = sm + 2424;     // 1632 x[2][48][17]
    float* sh_p1  = sm + 4056;     // 1632 pre1[2][48][17]
    uint*  sh_h2u = (uint*)(sm + 5688);   // 128 h fp16 pairs [2][64]
    uint*  sh_c2u = (uint*)(sm + 5816);   // 128
    uint*  sh_u2  = (uint*)(sm + 5944);   // 268 (2x132 used; 16B-aligned bases)
    _Float16* sh_p2h = (_Float16*)(sm + 6212);  // 12480 halves [2][48][130]: pre2 then ud
    _Float16* sh_fnh = (_Float16*)(sm + 12452); // 12288 halves [2][48][128]: fin
    uint*     sh_fn2 = (uint*)(sm + 12452);     // pair view [2][48][64]
    // total 18596 floats = 74,384 B -> 2 blocks/CU (148.8 KB of 160)

    const int tid = threadIdx.x;
    const int b0  = blockIdx.x * BBLK;
    const _Float16* wsh = (const _Float16*)ws;

    // ---- phase 0 ----
    for (int idx = tid; idx < BBLK*T_ENC*FDIM; idx += NTH) {
        int b = idx / (T_ENC*FDIM), r = idx % (T_ENC*FDIM), t = r / FDIM, f = r % FDIM;
        sh_x[idx] = ipq[((size_t)(b0 + b)*T_ENC + t)*18 + 1 + f];
    }
    if (tid < 256) { sh_h[tid] = 0.f; sh_c[tid] = 0.f; }
    if (tid < 128) { sh_h2u[tid] = 0u; sh_c2u[tid] = 0u; }
    if (tid < BBLK*T_ENC) {
        int b = tid / T_ENC, t = tid % T_ENC;
        ws[F_MID + ((size_t)(b0 + b)*T_ENC + t)*129 + 128] = labp[(size_t)(b0 + b)*T_ENC + t];
    }
    __syncthreads();
    for (int idx = tid; idx < BBLK*T_ENC*FDIM; idx += NTH) {   // pre1[b][s][f]
        int b = idx / (T_ENC*FDIM), r = idx % (T_ENC*FDIM), s = r / FDIM, f = r % FDIM;
        float acc = Ue1b[s];
        #pragma unroll 4
        for (int t = 0; t < T_ENC; ++t) acc = fmaf(sh_x[(b*T_ENC+t)*FDIM + f], Ue1W[s*T_ENC + t], acc);
        sh_p1[idx] = acc;
    }
    __syncthreads();

    // ============================ stage 1 ============================
    const float ve1b = Ve1b[0];
    for (int t = 0; t < T_ENC; ++t) {
        we_phase2w((const uint*)(wsh + H_WE1T), sh_h2u, sh_c2u, sh_we, tid);
        __syncthreads();
        if (tid < 272) {                          // score[b][f]: 2b x 17f x 8q, 6 tanh
            int b = tid / 136, r = tid % 136, f = r >> 3, q = r & 7;
            float acc = 0.f;
            for (int s = q; s < 48; s += 8)
                acc += fast_tanh(sh_we[b*48 + s] + sh_p1[(b*T_ENC + s)*FDIM + f]) * Ve1[s];
            acc += __shfl_xor(acc, 1);
            acc += __shfl_xor(acc, 2);
            acc += __shfl_xor(acc, 4);
            if (q == 0) sh_sc[b*132 + f] = acc + ve1b;
        }
        __syncthreads();
        softmax2(sh_sc, sh_at, FDIM, tid);
        __syncthreads();
        if (tid < BBLK*152) {                     // u fp16 = [x_t*attn(17), h(128), pad]
            int b = tid / 152, kk = tid % 152;
            float v;
            if (kk < FDIM)        v = sh_x[(b*T_ENC + t)*FDIM + kk] * sh_at[b*132 + kk];
            else if (kk < FDIM+H) v = sh_h[b*H + (kk - FDIM)];
            else                  v = 0.f;
            float vnb = __shfl_xor(v, 1);
            if (!(kk & 1)) sh_u2[b*132 + (kk >> 1)] = pack2(v, vnb);
        }
        __syncthreads();
        lstm_gates2w<19>((const float4*)(wsh + H_WT1), ws + F_B1, sh_u2, sh_g, tid);
        __syncthreads();
        if (tid < 256) {                          // LSTM update; mid row -> ws
            int b = tid >> 7, jj = tid & 127;
            float gi = sh_g[b*512 + jj],       gf = sh_g[b*512 + 128 + jj];
            float gg = sh_g[b*512 + 256 + jj], go = sh_g[b*512 + 384 + jj];
            float c2v = fast_sigm(gf)*sh_c[tid] + fast_sigm(gi)*fast_tanh(gg);
            float hn  = fast_sigm(go)*fast_tanh(c2v);
            sh_c[tid] = c2v; sh_h[tid] = hn;
            ws[F_MID + ((size_t)(b0 + b)*T_ENC + t)*129 + jj] = hn;
            float hnb = __shfl_xor(hn, 1), cnb = __shfl_xor(c2v, 1);
            if (!(jj & 1)) {
                sh_h2u[b*64 + (jj >> 1)] = pack2(hn, hnb);
                sh_c2u[b*64 + (jj >> 1)] = pack2(c2v, cnb);
            }
        }
        __syncthreads();
    }

    // ---- transition: pre2 fp16 -> LDS [b][s][130]; reset state ----
    for (int idx = tid; idx < BBLK*48*129; idx += NTH) {
        int b = idx / (48*129), r = idx % (48*129), s = r / 129, f = r % 129;
        const float* midb = ws + F_MID + (size_t)(b0 + b)*T_ENC*129 + f;
        float acc = Ue2b[s];
        #pragma unroll 4
        for (int t2 = 0; t2 < T_ENC; ++t2) acc = fmaf(midb[t2*129], Ue2W[s*48 + t2], acc);
        sh_p2h[(b*48 + s)*130 + f] = (_Float16)acc;
    }
    if (tid < 256) { sh_h[tid] = 0.f; sh_c[tid] = 0.f; }
    if (tid < 128) { sh_h2u[tid] = 0u; sh_c2u[tid] = 0u; }
    __syncthreads();

    // ============================ stage 2 ============================
    const float ve2b = Ve2b[0];
    for (int t = 0; t < T_ENC; ++t) {
        we_phase2w((const uint*)(wsh + H_WE2T), sh_h2u, sh_c2u, sh_we, tid);
        __syncthreads();
        if (tid < 516) {                          // score partials: 2b x 129f x 2 s-halves
            int b = tid / 258, r = tid % 258;
            int f  = (r < 129) ? r : r - 129;
            int s0 = (r < 129) ? 0 : 24;
            const _Float16* p2 = sh_p2h + (b*48)*130 + f;
            const float* wv = sh_we + b*48;
            float acc = 0.f;
            #pragma unroll 4
            for (int s = s0; s < s0 + 24; ++s)
                acc += fast_tanh(wv[s] + (float)p2[s*130]) * Ve2[s];
            ((r < 129) ? sh_sc : sh_sc2)[b*132 + f] = acc;
        }
        __syncthreads();
        if (tid < 258) {
            int b = tid / 129, f = tid % 129;
            sh_sc[b*132 + f] += sh_sc2[b*132 + f] + ve2b;
        }
        __syncthreads();
        softmax2(sh_sc, sh_at, 129, tid);
        __syncthreads();
        if (tid < BBLK*264) {                     // u fp16 = [m_t*attn(129), h(128), pad]
            int b = tid / 264, kk = tid % 264;
            const float* midrow = ws + F_MID + ((size_t)(b0 + b)*T_ENC + t)*129;
            float v;
            if (kk < 129)      v = midrow[kk] * sh_at[b*132 + kk];
            else if (kk < 257) v = sh_h[b*H + (kk - 129)];
            else               v = 0.f;
            float vnb = __shfl_xor(v, 1);
            if (!(kk & 1)) sh_u2[b*132 + (kk >> 1)] = pack2(v, vnb);
        }
        __syncthreads();
        lstm_gates2w<33>((const float4*)(wsh + H_WT2), ws + F_B2, sh_u2, sh_g, tid);
        __syncthreads();
        if (tid < 256) {                          // update; fin fp16 -> LDS only
            int b = tid >> 7, jj = tid & 127;
            float gi = sh_g[b*512 + jj],       gf = sh_g[b*512 + 128 + jj];
            float gg = sh_g[b*512 + 256 + jj], go = sh_g[b*512 + 384 + jj];
            float c2v = fast_sigm(gf)*sh_c[tid] + fast_sigm(gi)*fast_tanh(gg);
            float hn  = fast_sigm(go)*fast_tanh(c2v);
            sh_c[tid] = c2v; sh_h[tid] = hn;
            sh_fnh[(b*T_ENC + t)*128 + jj] = (_Float16)hn;
            float hnb = __shfl_xor(hn, 1), cnb = __shfl_xor(c2v, 1);
            if (!(jj & 1)) {
                sh_h2u[b*64 + (jj >> 1)] = pack2(hn, hnb);
                sh_c2u[b*64 + (jj >> 1)] = pack2(c2v, cnb);
            }
        }
        __syncthreads();
    }

    // ---- transition: ud = fin @ Ud^T + Udb, LDS->LDS (overwrites dead pre2) ----
    {
        int b = tid >> 9, r = tid & 511, hh = r & 127, tg = r >> 7;   // tg 0..3
        float acc[12];
        float ub = Udb[hh];
        #pragma unroll
        for (int i = 0; i < 12; ++i) acc[i] = ub;
        const uint* UT2  = (const uint*)(wsh + H_UDT);
        const uint* fin2 = sh_fn2 + b*T_ENC*64;
        for (int k2 = 0; k2 < 64; ++k2) {
            h2_t w2 = uh(UT2[k2*128 + hh]);
            #pragma unroll
            for (int i = 0; i < 12; ++i)
                acc[i] = dot2f(uh(fin2[(tg + 4*i)*64 + k2]), w2, acc[i]);
        }
        #pragma unroll
        for (int i = 0; i < 12; ++i)
            sh_p2h[(b*T_ENC + tg + 4*i)*130 + hh] = (_Float16)acc[i];   // ud[b][t][h]
    }
    if (tid < 256) { sh_h[tid] = 0.f; sh_c[tid] = 0.f; }
    if (tid < 128) { sh_h2u[tid] = 0u; sh_c2u[tid] = 0u; }
    __syncthreads();

    // ============================ decoder ============================
    const float vdb = Vdb[0], rb = regb[0];
    for (int st = 0; st < 30; ++st) {
        {   // wd partials: 2b x 4kq x 128sp -> sh_g[b*512 + kq*128 + sp]
            int b = tid >> 9, r = tid & 511, kq = r >> 7, sp = r & 127;
            const uint* st2 = ((kq < 2) ? sh_h2u : sh_c2u) + b*64 + (kq & 1)*32;
            const uint* W2  = (const uint*)(wsh + H_WDT) + (kq*32)*128 + sp;
            float acc = 0.f;
            #pragma unroll 8
            for (int i = 0; i < 32; ++i)
                acc = dot2f(uh(st2[i]), uh(W2[i*128]), acc);
            sh_g[b*512 + kq*128 + sp] = acc;
        }
        __syncthreads();
        if (tid < 768) {                           // score[b][t]: 2b x 48t x 8q, 16 tanh
            int b = tid / 384, r = tid % 384, tt = r >> 3, q = r & 7, h0 = q*16;
            const _Float16* udrow = sh_p2h + (b*T_ENC + tt)*130;
            const float* pg = sh_g + b*512;
            float acc = 0.f;
            #pragma unroll 4
            for (int kk = 0; kk < 16; ++kk) {
                int hh = h0 + kk;
                float wd = pg[hh] + pg[128 + hh] + pg[256 + hh] + pg[384 + hh];
                acc += fast_tanh(wd + (float)udrow[hh]) * Vd[hh];
            }
            acc += __shfl_xor(acc, 1);
            acc += __shfl_xor(acc, 2);
            acc += __shfl_xor(acc, 4);
            if (q == 0) sh_sc[b*132 + tt] = acc + vdb;
        }
        __syncthreads();
        softmax2(sh_sc, sh_at, 48, tid);
        __syncthreads();
        {                                          // din[b][h]: 2b x 128h x 4q, 12 fma
            int b = tid >> 9, r = tid & 511, hh = r >> 2, q = r & 3;
            const _Float16* fb = sh_fnh + b*T_ENC*128 + hh;
            float acc = 0.f;
            for (int tt = q; tt < 48; tt += 4)
                acc = fmaf(sh_at[b*132 + tt], (float)fb[tt*128], acc);
            acc += __shfl_xor(acc, 1);
            acc += __shfl_xor(acc, 2);             // full din[hh] on 4 lanes
            float anb = __shfl_xor(acc, 4);        // din[hh^1]
            if (q == 0 && !(hh & 1)) sh_u2[b*132 + (hh >> 1)] = pack2(acc, anb);
        }
        if (tid < 128) {                           // u[64..127] = h pairs
            int b = tid >> 6, i = tid & 63;
            sh_u2[b*132 + 64 + i] = sh_h2u[b*64 + i];
        }
        __syncthreads();
        lstm_gates2w<32>((const float4*)(wsh + H_WTD), ws + F_BD, sh_u2, sh_g, tid);
        __syncthreads();
        if (tid < 256) {
            int b = tid >> 7, jj = tid & 127;
            float gi = sh_g[b*512 + jj],       gf = sh_g[b*512 + 128 + jj];
            float gg = sh_g[b*512 + 256 + jj], go = sh_g[b*512 + 384 + jj];
            float c2v = fast_sigm(gf)*sh_c[tid] + fast_sigm(gi)*fast_tanh(gg);
            float hn  = fast_sigm(go)*fast_tanh(c2v);
            sh_c[tid] = c2v; sh_h[tid] = hn;
            float hnb = __shfl_xor(hn, 1), cnb = __shfl_xor(c2v, 1);
            if (!(jj & 1)) {
                sh_h2u[b*64 + (jj >> 1)] = pack2(hn, hnb);
                sh_c2u[b*64 + (jj >> 1)] = pack2(c2v, cnb);
            }
        }
        __syncthreads();
        if (st >= 6 && tid < 128) {                // out[b][st-6] (reads only sh_h)
            int b = tid >> 6, l = tid & 63;
            float v = sh_h[b*H + l]*regW[l] + sh_h[b*H + 64 + l]*regW[64 + l];
            for (int o = 32; o; o >>= 1) v += __shfl_xor(v, o);
            if (l == 0) out[(size_t)(b0 + b)*24 + (st - 6)] = v + rb;
        }
        // next wd phase writes sh_g, reads h2u/c2u (both settled) -> no extra barrier
    }
}

extern "C" void kernel_launch(void* const* d_in, const int* in_sizes, int n_in,
                              void* d_out, int out_size, void* d_ws, size_t ws_size,
                              hipStream_t stream)
{
    const float* ipq   = (const float*)d_in[0];
    const float* labp  = (const float*)d_in[1];
    const float* Ue1W  = (const float*)d_in[2];
    const float* Ue1b  = (const float*)d_in[3];
    const float* We1W  = (const float*)d_in[4];
    const float* Ve1   = (const float*)d_in[5];
    const float* Ve1b  = (const float*)d_in[6];
    const float* Ue2W  = (const float*)d_in[7];
    const float* Ue2b  = (const float*)d_in[8];
    const float* We2W  = (const float*)d_in[9];
    const float* Ve2   = (const float*)d_in[10];
    const float* Ve2b  = (const float*)d_in[11];
    const float* UdW   = (const float*)d_in[12];
    const float* Udb   = (const float*)d_in[13];
    const float* WdW   = (const float*)d_in[14];
    const float* Vd    = (const float*)d_in[15];
    const float* Vdb   = (const float*)d_in[16];
    const float* e1Wih = (const float*)d_in[17];
    const float* e1Whh = (const float*)d_in[18];
    const float* e1bih = (const float*)d_in[19];
    const float* e1bhh = (const float*)d_in[20];
    const float* e2Wih = (const float*)d_in[21];
    const float* e2Whh = (const float*)d_in[22];
    const float* e2bih = (const float*)d_in[23];
    const float* e2bhh = (const float*)d_in[24];
    const float* dWih  = (const float*)d_in[25];
    const float* dWhh  = (const float*)d_in[26];
    const float* dbih  = (const float*)d_in[27];
    const float* dbhh  = (const float*)d_in[28];
    const float* regW  = (const float*)d_in[29];
    const float* regb  = (const float*)d_in[30];
    float* ws  = (float*)d_ws;
    float* out = (float*)d_out;

    // weights: 417792 halves; biases: 1536 floats
    prep_kernel<<<(417792 + 1536 + 255)/256, 256, 0, stream>>>(
        We1W, We2W, WdW, UdW,
        e1Wih, e1Whh, e1bih, e1bhh,
        e2Wih, e2Whh, e2bih, e2bhh,
        dWih, dWhh, dbih, dbhh, ws);

    const size_t smem = 18596u * sizeof(float);   // 74,384 B -> 2 blocks/CU
    hipFuncSetAttribute((const void*)dstp_main,
                        hipFuncAttributeMaxDynamicSharedMemorySize, (int)smem);
    dstp_main<<<GRID, NTH, smem, stream>>>(
        ipq, labp, Ue1W, Ue1b, Ve1, Ve1b,
        Ue2W, Ue2b, Ve2, Ve2b,
        Udb, Vd, Vdb, regW, regb, ws, out);
}

// Round 9
// 1484.533 us; speedup vs baseline: 2.1156x; 2.1156x over previous
//
#include <hip/hip_runtime.h>

// DSTP-RNN: B=1024, T_ENC=48, 30 decoder steps, H=128, F=17.
// Round 9 (= round 8 resubmit; round-8 bench was GPUAcquisitionTimeout, never ran):
// round-5 config (BBLK=2, GRID=512, NTH=512, launch_bounds(512,6) -> VGPR ~40,
// NO spills; rounds 6/7 regressed from launch_bounds(...,8) forcing VGPR=32 ->
// scratch thrash, 3GB HBM). Adds: cheap tanh/sigm (5/4 ops), fin in LDS fp16
// (no global fin traffic), wider score/din phases.

#define T_ENC 48
#define H 128
#define FDIM 17
#define BBLK 2
#define NTH 512
#define GRID 512

// ---- ws HALF offsets ----
#define H_WT1   0          // 19*512*8  = 77824  (e1 gates, [k8][j][8h], K pad 152)
#define H_WT2   77824      // 33*512*8  = 135168 (e2, K pad 264)
#define H_WTD   212992     // 32*512*8  = 131072 (dec, K=256)
#define H_WE1T  344064     // 128*48*2  = 12288  (We1^T pairs, uint idx k2*48+s)
#define H_WE2T  356352     // 12288
#define H_WDT   368640     // 128*128*2 = 32768  (Wd^T pairs, uint idx k2*128+sp)
#define H_UDT   401408     // 64*128*2  = 16384  (Ud^T pairs, uint idx k2*128+h)
// halves end at 417792 -> 835584 B = 208896 floats
// ---- ws FLOAT offsets ----
#define F_B1    208896
#define F_B2    209408
#define F_BD    209920
#define F_MID   210432     // 1024*48*129 fp32 mid [b][t][129] (body+label col)

typedef _Float16 h2_t __attribute__((ext_vector_type(2)));
union H2U { h2_t h; uint u; float f; };

__device__ __forceinline__ h2_t uh(uint v){ H2U x; x.u = v; return x.h; }
__device__ __forceinline__ h2_t fh(float v){ H2U x; x.f = v; return x.h; }
__device__ __forceinline__ uint pack2(float a, float b){
    H2U x; x.h[0] = (_Float16)a; x.h[1] = (_Float16)b; return x.u;
}
__device__ __forceinline__ float dot2f(h2_t a, h2_t b, float c){
#if __has_builtin(__builtin_amdgcn_fdot2)
    return __builtin_amdgcn_fdot2(a, b, c, false);
#else
    return c + (float)a[0]*(float)b[0] + (float)a[1]*(float)b[1];
#endif
}

// sigm: 4 VALU ops (mul, exp2, add, rcp). rcp = v_rcp_f32 (1 ulp).
__device__ __forceinline__ float fast_sigm(float x){
    return __builtin_amdgcn_rcpf(1.0f + __expf(-x));
}
// tanh = 1 - 2/(1+e^{2x}): 5 ops, clamp-free (e->inf => 1, e->0 => -1).
__device__ __forceinline__ float fast_tanh(float x){
    float e = __expf(2.0f * x);
    return fmaf(-2.0f, __builtin_amdgcn_rcpf(1.0f + e), 1.0f);
}

// ---------------- prologue: transpose/fuse weights into ws (fp16) ----------------
__global__ void prep_kernel(const float* __restrict__ We1W, const float* __restrict__ We2W,
                            const float* __restrict__ WdW,  const float* __restrict__ UdW,
                            const float* __restrict__ e1Wih, const float* __restrict__ e1Whh,
                            const float* __restrict__ e1bih, const float* __restrict__ e1bhh,
                            const float* __restrict__ e2Wih, const float* __restrict__ e2Whh,
                            const float* __restrict__ e2bih, const float* __restrict__ e2bhh,
                            const float* __restrict__ dWih,  const float* __restrict__ dWhh,
                            const float* __restrict__ dbih,  const float* __restrict__ dbhh,
                            float* __restrict__ ws)
{
    int idx = blockIdx.x * blockDim.x + threadIdx.x;
    _Float16* wsh = (_Float16*)ws;
    if (idx < 77824) {                       // WT1 [k8][j][8]: k<17 Wih, k<145 Whh, else 0
        int k8 = idx >> 12, r = idx & 4095, j = r >> 3, kq = r & 7, k = k8*8 + kq;
        float v = 0.f;
        if (k < 17) v = e1Wih[j*17 + k]; else if (k < 145) v = e1Whh[j*128 + (k-17)];
        wsh[H_WT1 + idx] = (_Float16)v; return;
    }
    idx -= 77824;
    if (idx < 135168) {                      // WT2: k<129 Wih, k<257 Whh, else 0 (pad 264)
        int k8 = idx >> 12, r = idx & 4095, j = r >> 3, kq = r & 7, k = k8*8 + kq;
        float v = 0.f;
        if (k < 129) v = e2Wih[j*129 + k]; else if (k < 257) v = e2Whh[j*128 + (k-129)];
        wsh[H_WT2 + idx] = (_Float16)v; return;
    }
    idx -= 135168;
    if (idx < 131072) {                      // WTD: k<128 Wih else Whh (K=256)
        int k8 = idx >> 12, r = idx & 4095, j = r >> 3, kq = r & 7, k = k8*8 + kq;
        float v = (k < 128) ? dWih[j*128 + k] : dWhh[j*128 + (k-128)];
        wsh[H_WTD + idx] = (_Float16)v; return;
    }
    idx -= 131072;
    if (idx < 12288) {                       // We1^T pairs
        int pr = idx >> 1, p = idx & 1, k2 = pr / 48, s = pr % 48;
        wsh[H_WE1T + idx] = (_Float16)We1W[s*256 + 2*k2 + p]; return;
    }
    idx -= 12288;
    if (idx < 12288) {
        int pr = idx >> 1, p = idx & 1, k2 = pr / 48, s = pr % 48;
        wsh[H_WE2T + idx] = (_Float16)We2W[s*256 + 2*k2 + p]; return;
    }
    idx -= 12288;
    if (idx < 32768) {                       // Wd^T pairs
        int pr = idx >> 1, p = idx & 1, k2 = pr >> 7, sp = pr & 127;
        wsh[H_WDT + idx] = (_Float16)WdW[sp*256 + 2*k2 + p]; return;
    }
    idx -= 32768;
    if (idx < 16384) {                       // Ud^T pairs
        int pr = idx >> 1, p = idx & 1, k2 = pr >> 7, hh = pr & 127;
        wsh[H_UDT + idx] = (_Float16)UdW[hh*128 + 2*k2 + p]; return;
    }
    idx -= 16384;
    if (idx < 512) { ws[F_B1 + idx] = e1bih[idx] + e1bhh[idx]; return; }
    idx -= 512;
    if (idx < 512) { ws[F_B2 + idx] = e2bih[idx] + e2bhh[idx]; return; }
    idx -= 512;
    if (idx < 512) { ws[F_BD + idx] = dbih[idx] + dbhh[idx]; return; }
}

// gate matmul via dot2: g[b][j] = bias[j] + sum_k u[b][k]*W[k][j]; j = tid, 2 batches
template<int K8>
__device__ __forceinline__ void lstm_gates2h(const float4* __restrict__ W8,
                                             const float* __restrict__ bias,
                                             const uint* u2, float* g, int tid)
{
    float a0 = bias[tid], a1 = a0;
    #pragma unroll 4
    for (int k8 = 0; k8 < K8; ++k8) {
        float4 w  = W8[k8*512 + tid];                  // 8 halves (weights k..k+7)
        float4 ua = *(const float4*)(u2 + 4*k8);       // 8 halves batch 0
        float4 ub = *(const float4*)(u2 + 132 + 4*k8); // 8 halves batch 1
        a0 = dot2f(fh(w.x), fh(ua.x), a0); a0 = dot2f(fh(w.y), fh(ua.y), a0);
        a0 = dot2f(fh(w.z), fh(ua.z), a0); a0 = dot2f(fh(w.w), fh(ua.w), a0);
        a1 = dot2f(fh(w.x), fh(ub.x), a1); a1 = dot2f(fh(w.y), fh(ub.y), a1);
        a1 = dot2f(fh(w.z), fh(ub.z), a1); a1 = dot2f(fh(w.w), fh(ub.w), a1);
    }
    g[tid] = a0; g[512 + tid] = a1;
}

// softmax over n entries per batch row (2 rows, stride 132), 32 threads per b
__device__ __forceinline__ void softmax2(float* sc, float* at, int n, int tid)
{
    if (tid < 64) {
        int b = tid >> 5, i = tid & 31, base = b*132;
        float m = -1e30f;
        for (int f = i; f < n; f += 32) m = fmaxf(m, sc[base + f]);
        for (int o = 16; o; o >>= 1) m = fmaxf(m, __shfl_xor(m, o, 32));
        float ssum = 0.f;
        for (int f = i; f < n; f += 32) { float p = __expf(sc[base+f] - m); at[base+f] = p; ssum += p; }
        for (int o = 16; o; o >>= 1) ssum += __shfl_xor(ssum, o, 32);
        float inv = __fdividef(1.f, ssum);
        for (int f = i; f < n; f += 32) at[base + f] *= inv;
    }
}

// we[b][s] = [h;c] @ W^T via dot2; 384 threads, quad split-K (64 k each = 32 pairs)
__device__ __forceinline__ void we_phase_h(const uint* __restrict__ W2,
                                           const uint* h2, const uint* c2,
                                           float* sh_we, int tid)
{
    if (tid < 384) {
        int b = tid / 192, r = tid % 192, s = r >> 2, kq = r & 3;
        const uint* st2 = ((kq < 2) ? h2 : c2) + b*64 + (kq & 1)*32;  // 32 pairs
        const uint* w2  = W2 + (kq*32)*48 + s;
        float acc = 0.f;
        #pragma unroll 8
        for (int kk = 0; kk < 32; ++kk)
            acc = dot2f(uh(st2[kk]), uh(w2[kk*48]), acc);
        acc += __shfl_xor(acc, 1);
        acc += __shfl_xor(acc, 2);
        if (kq == 0) sh_we[b*48 + s] = acc;
    }
}

__global__ __launch_bounds__(NTH, 6)
void dstp_main(const float* __restrict__ ipq,  const float* __restrict__ labp,
               const float* __restrict__ Ue1W, const float* __restrict__ Ue1b,
               const float* __restrict__ Ve1,  const float* __restrict__ Ve1b,
               const float* __restrict__ Ue2W, const float* __restrict__ Ue2b,
               const float* __restrict__ Ve2,  const float* __restrict__ Ve2b,
               const float* __restrict__ Udb,
               const float* __restrict__ Vd,   const float* __restrict__ Vdb,
               const float* __restrict__ regW, const float* __restrict__ regb,
               float* __restrict__ ws, float* __restrict__ out)
{
    extern __shared__ float sm[];
    float* sh_h   = sm;            // 256  h[2][128] fp32
    float* sh_c   = sm + 256;      // 256
    float* sh_we  = sm + 512;      // 96   we[2][48]
    float* sh_sc  = sm + 608;      // 264  scores [2][132]
    float* sh_sc2 = sm + 872;      // 264  score partials
    float* sh_at  = sm + 1136;     // 264  attention
    float* sh_g   = sm + 1400;     // 1024 gates [2][512] / wd partials
    float* sh_x   = sm + 2424;     // 1632 x[2][48][17]
    float* sh_p1  = sm + 4056;     // 1632 pre1[2][48][17]
    uint*  sh_h2u = (uint*)(sm + 5688);   // 128 h fp16 pairs [2][64]
    uint*  sh_c2u = (uint*)(sm + 5816);   // 128
    uint*  sh_u2  = (uint*)(sm + 5944);   // 268 (2x132 used; 16B-aligned bases)
    _Float16* sh_p2h = (_Float16*)(sm + 6212);  // 12480 halves [2][48][130]: pre2 then ud
    _Float16* sh_fnh = (_Float16*)(sm + 12452); // 12288 halves [2][48][128]: fin
    uint*     sh_fn2 = (uint*)(sm + 12452);     // pair view [2][48][64]
    // total 18596 floats = 74,384 B -> 2 blocks/CU

    const int tid = threadIdx.x;
    const int b0  = blockIdx.x * BBLK;
    const _Float16* wsh = (const _Float16*)ws;

    // ---- phase 0 ----
    for (int idx = tid; idx < BBLK*T_ENC*FDIM; idx += NTH) {
        int b = idx / (T_ENC*FDIM), r = idx % (T_ENC*FDIM), t = r / FDIM, f = r % FDIM;
        sh_x[idx] = ipq[((size_t)(b0 + b)*T_ENC + t)*18 + 1 + f];
    }
    if (tid < 256) { sh_h[tid] = 0.f; sh_c[tid] = 0.f; }
    if (tid < 128) { sh_h2u[tid] = 0u; sh_c2u[tid] = 0u; }
    if (tid < BBLK*T_ENC) {                       // mid label column (f=128)
        int b = tid / T_ENC, t = tid % T_ENC;
        ws[F_MID + ((size_t)(b0 + b)*T_ENC + t)*129 + 128] = labp[(size_t)(b0 + b)*T_ENC + t];
    }
    __syncthreads();
    for (int idx = tid; idx < BBLK*T_ENC*FDIM; idx += NTH) {   // pre1[b][s][f]
        int b = idx / (T_ENC*FDIM), r = idx % (T_ENC*FDIM), s = r / FDIM, f = r % FDIM;
        float acc = Ue1b[s];
        #pragma unroll 4
        for (int t = 0; t < T_ENC; ++t) acc = fmaf(sh_x[(b*T_ENC+t)*FDIM + f], Ue1W[s*T_ENC + t], acc);
        sh_p1[idx] = acc;
    }
    __syncthreads();

    // ============================ stage 1 ============================
    const float ve1b = Ve1b[0];
    for (int t = 0; t < T_ENC; ++t) {
        we_phase_h((const uint*)(wsh + H_WE1T), sh_h2u, sh_c2u, sh_we, tid);
        __syncthreads();
        if (tid < 272) {                          // score[b][f]: 2b x 17f x 8q, 6 tanh
            int b = tid / 136, r = tid % 136, f = r >> 3, q = r & 7;
            float acc = 0.f;
            for (int s = q; s < 48; s += 8)
                acc += fast_tanh(sh_we[b*48 + s] + sh_p1[(b*T_ENC + s)*FDIM + f]) * Ve1[s];
            acc += __shfl_xor(acc, 1);
            acc += __shfl_xor(acc, 2);
            acc += __shfl_xor(acc, 4);
            if (q == 0) sh_sc[b*132 + f] = acc + ve1b;
        }
        __syncthreads();
        softmax2(sh_sc, sh_at, FDIM, tid);
        __syncthreads();
        if (tid < BBLK*152) {                     // u fp16 = [x_t*attn(17), h(128), pad]
            int b = tid / 152, kk = tid % 152;
            float v;
            if (kk < FDIM)        v = sh_x[(b*T_ENC + t)*FDIM + kk] * sh_at[b*132 + kk];
            else if (kk < FDIM+H) v = sh_h[b*H + (kk - FDIM)];
            else                  v = 0.f;
            float vnb = __shfl_xor(v, 1);
            if (!(kk & 1)) sh_u2[b*132 + (kk >> 1)] = pack2(v, vnb);
        }
        __syncthreads();
        lstm_gates2h<19>((const float4*)(wsh + H_WT1), ws + F_B1, sh_u2, sh_g, tid);
        __syncthreads();
        if (tid < 256) {                          // LSTM update; mid row -> ws (fp32)
            int b = tid >> 7, jj = tid & 127;
            float gi = sh_g[b*512 + jj],       gf = sh_g[b*512 + 128 + jj];
            float gg = sh_g[b*512 + 256 + jj], go = sh_g[b*512 + 384 + jj];
            float c2v = fast_sigm(gf)*sh_c[tid] + fast_sigm(gi)*fast_tanh(gg);
            float hn  = fast_sigm(go)*fast_tanh(c2v);
            sh_c[tid] = c2v; sh_h[tid] = hn;
            ws[F_MID + ((size_t)(b0 + b)*T_ENC + t)*129 + jj] = hn;
            float hnb = __shfl_xor(hn, 1), cnb = __shfl_xor(c2v, 1);
            if (!(jj & 1)) {
                sh_h2u[b*64 + (jj >> 1)] = pack2(hn, hnb);
                sh_c2u[b*64 + (jj >> 1)] = pack2(c2v, cnb);
            }
        }
        __syncthreads();
    }

    // ---- transition: pre2 fp16 -> LDS [b][s][130]; reset state ----
    for (int idx = tid; idx < BBLK*48*129; idx += NTH) {
        int b = idx / (48*129), r = idx % (48*129), s = r / 129, f = r % 129;
        const float* midb = ws + F_MID + (size_t)(b0 + b)*T_ENC*129 + f;
        float acc = Ue2b[s];
        #pragma unroll 4
        for (int t2 = 0; t2 < T_ENC; ++t2) acc = fmaf(midb[t2*129], Ue2W[s*48 + t2], acc);
        sh_p2h[(b*48 + s)*130 + f] = (_Float16)acc;
    }
    if (tid < 256) { sh_h[tid] = 0.f; sh_c[tid] = 0.f; }
    if (tid < 128) { sh_h2u[tid] = 0u; sh_c2u[tid] = 0u; }
    __syncthreads();

    // ============================ stage 2 ============================
    const float ve2b = Ve2b[0];
    for (int t = 0; t < T_ENC; ++t) {
        we_phase_h((const uint*)(wsh + H_WE2T), sh_h2u, sh_c2u, sh_we, tid);
        __syncthreads();
        for (int p = tid; p < 516; p += NTH) {    // score partials: 2b x 129f x 2 s-halves
            int b = p / 258, r = p % 258;
            int f  = (r < 129) ? r : r - 129;
            int s0 = (r < 129) ? 0 : 24;
            const _Float16* p2 = sh_p2h + (b*48)*130 + f;
            const float* wv = sh_we + b*48;
            float acc = 0.f;
            #pragma unroll 4
            for (int s = s0; s < s0 + 24; ++s)
                acc += fast_tanh(wv[s] + (float)p2[s*130]) * Ve2[s];
            ((r < 129) ? sh_sc : sh_sc2)[b*132 + f] = acc;
        }
        __syncthreads();
        if (tid < 258) {
            int b = tid / 129, f = tid % 129;
            sh_sc[b*132 + f] += sh_sc2[b*132 + f] + ve2b;
        }
        __syncthreads();
        softmax2(sh_sc, sh_at, 129, tid);
        __syncthreads();
        for (int idx = tid; idx < BBLK*264; idx += NTH) {   // u fp16 = [m_t*attn, h, pad]
            int b = idx / 264, kk = idx % 264;
            const float* midrow = ws + F_MID + ((size_t)(b0 + b)*T_ENC + t)*129;
            float v;
            if (kk < 129)      v = midrow[kk] * sh_at[b*132 + kk];
            else if (kk < 257) v = sh_h[b*H + (kk - 129)];
            else               v = 0.f;
            float vnb = __shfl_xor(v, 1);
            if (!(idx & 1)) sh_u2[b*132 + (kk >> 1)] = pack2(v, vnb);
        }
        __syncthreads();
        lstm_gates2h<33>((const float4*)(wsh + H_WT2), ws + F_B2, sh_u2, sh_g, tid);
        __syncthreads();
        if (tid < 256) {                          // update; fin fp16 -> LDS only
            int b = tid >> 7, jj = tid & 127;
            float gi = sh_g[b*512 + jj],       gf = sh_g[b*512 + 128 + jj];
            float gg = sh_g[b*512 + 256 + jj], go = sh_g[b*512 + 384 + jj];
            float c2v = fast_sigm(gf)*sh_c[tid] + fast_sigm(gi)*fast_tanh(gg);
            float hn  = fast_sigm(go)*fast_tanh(c2v);
            sh_c[tid] = c2v; sh_h[tid] = hn;
            sh_fnh[(b*T_ENC + t)*128 + jj] = (_Float16)hn;
            float hnb = __shfl_xor(hn, 1), cnb = __shfl_xor(c2v, 1);
            if (!(jj & 1)) {
                sh_h2u[b*64 + (jj >> 1)] = pack2(hn, hnb);
                sh_c2u[b*64 + (jj >> 1)] = pack2(c2v, cnb);
            }
        }
        __syncthreads();
    }

    // ---- transition: ud = fin @ Ud^T + Udb, LDS->LDS (3 chunks x acc[8]) ----
    {
        const int hh = tid & 127;                 // fixed per thread (512 % 128 == 0)
        const uint* UT2 = (const uint*)(wsh + H_UDT);
        #pragma unroll
        for (int c = 0; c < 3; ++c) {
            float acc[8]; int rowb2[8]; int rowp[8];
            #pragma unroll
            for (int i = 0; i < 8; ++i) {
                int idx = (c*8 + i)*NTH + tid;    // over 2b*48t*128h = 12288
                int b = idx / 6144, r = idx % 6144, tt = r >> 7;
                rowb2[i] = (b*T_ENC + tt)*64;
                rowp[i]  = (b*T_ENC + tt)*130 + hh;
                acc[i] = Udb[hh];
            }
            for (int k2 = 0; k2 < 64; ++k2) {
                h2_t w2 = uh(UT2[k2*128 + hh]);
                #pragma unroll
                for (int i = 0; i < 8; ++i) acc[i] = dot2f(uh(sh_fn2[rowb2[i] + k2]), w2, acc[i]);
            }
            #pragma unroll
            for (int i = 0; i < 8; ++i) sh_p2h[rowp[i]] = (_Float16)acc[i];  // ud[b][t][h]
        }
    }
    if (tid < 256) { sh_h[tid] = 0.f; sh_c[tid] = 0.f; }
    if (tid < 128) { sh_h2u[tid] = 0u; sh_c2u[tid] = 0u; }
    __syncthreads();

    // ============================ decoder ============================
    const float vdb = Vdb[0], rb = regb[0];
    for (int st = 0; st < 30; ++st) {
        {   // wd partials: 2b x 2kh x 128sp -> sh_g[(b*2+kh)*128+sp], 64 dot2 each
            int b = tid >> 8, r = tid & 255, kh = r >> 7, sp = r & 127;
            const uint* st2 = (kh ? sh_c2u : sh_h2u) + b*64;
            const uint* W2  = (const uint*)(wsh + H_WDT) + (kh*64)*128 + sp;
            float acc = 0.f;
            #pragma unroll 8
            for (int kk = 0; kk < 64; ++kk)
                acc = dot2f(uh(st2[kk]), uh(W2[kk*128]), acc);
            sh_g[(b*2 + kh)*128 + sp] = acc;
        }
        __syncthreads();
        if (tid < 384) {                           // score[b][t]: 2b x 48t x 4q, 32 tanh
            int b = tid / 192, r = tid % 192, tt = r >> 2, q = r & 3, h0 = q*32;
            const _Float16* udrow = sh_p2h + (b*T_ENC + tt)*130;
            const float* pg = sh_g + b*256;
            float acc = 0.f;
            #pragma unroll 4
            for (int kk = 0; kk < 32; ++kk) {
                int hh = h0 + kk;
                float wd = pg[hh] + pg[128 + hh];
                acc += fast_tanh(wd + (float)udrow[hh]) * Vd[hh];
            }
            acc += __shfl_xor(acc, 1);
            acc += __shfl_xor(acc, 2);
            if (q == 0) sh_sc[b*132 + tt] = acc + vdb;
        }
        __syncthreads();
        softmax2(sh_sc, sh_at, 48, tid);
        __syncthreads();
        {                                          // din[b][h]: 2b x 128h x 2q, 24 fma
            int b = tid >> 8, r = tid & 255, hh = r >> 1, q = r & 1;
            const _Float16* fb = sh_fnh + b*T_ENC*128 + hh;
            float acc = 0.f;
            for (int tt = q; tt < 48; tt += 2)
                acc = fmaf(sh_at[b*132 + tt], (float)fb[tt*128], acc);
            acc += __shfl_xor(acc, 1);             // full din[hh] on both lanes
            float anb = __shfl_xor(acc, 2);        // din[hh^1]
            if (!(tid & 3)) sh_u2[b*132 + (hh >> 1)] = pack2(acc, anb);
        }
        if (tid < 128) {                           // u[64..127] = h pairs
            int b = tid >> 6, i = tid & 63;
            sh_u2[b*132 + 64 + i] = sh_h2u[b*64 + i];
        }
        __syncthreads();
        lstm_gates2h<32>((const float4*)(wsh + H_WTD), ws + F_BD, sh_u2, sh_g, tid);
        __syncthreads();
        if (tid < 256) {
            int b = tid >> 7, jj = tid & 127;
            float gi = sh_g[b*512 + jj],       gf = sh_g[b*512 + 128 + jj];
            float gg = sh_g[b*512 + 256 + jj], go = sh_g[b*512 + 384 + jj];
            float c2v = fast_sigm(gf)*sh_c[tid] + fast_sigm(gi)*fast_tanh(gg);
            float hn  = fast_sigm(go)*fast_tanh(c2v);
            sh_c[tid] = c2v; sh_h[tid] = hn;
            float hnb = __shfl_xor(hn, 1), cnb = __shfl_xor(c2v, 1);
            if (!(jj & 1)) {
                sh_h2u[b*64 + (jj >> 1)] = pack2(hn, hnb);
                sh_c2u[b*64 + (jj >> 1)] = pack2(c2v, cnb);
            }
        }
        __syncthreads();
        if (st >= 6 && tid < 128) {                // out[b][st-6] (reads only sh_h)
            int b = tid >> 6, l = tid & 63;
            float v = sh_h[b*H + l]*regW[l] + sh_h[b*H + 64 + l]*regW[64 + l];
            for (int o = 32; o; o >>= 1) v += __shfl_xor(v, o);
            if (l == 0) out[(size_t)(b0 + b)*24 + (st - 6)] = v + rb;
        }
        // next wd phase writes sh_g, reads h2u/c2u (settled) -> no extra barrier
    }
}

extern "C" void kernel_launch(void* const* d_in, const int* in_sizes, int n_in,
                              void* d_out, int out_size, void* d_ws, size_t ws_size,
                              hipStream_t stream)
{
    const float* ipq   = (const float*)d_in[0];
    const float* labp  = (const float*)d_in[1];
    const float* Ue1W  = (const float*)d_in[2];
    const float* Ue1b  = (const float*)d_in[3];
    const float* We1W  = (const float*)d_in[4];
    const float* Ve1   = (const float*)d_in[5];
    const float* Ve1b  = (const float*)d_in[6];
    const float* Ue2W  = (const float*)d_in[7];
    const float* Ue2b  = (const float*)d_in[8];
    const float* We2W  = (const float*)d_in[9];
    const float* Ve2   = (const float*)d_in[10];
    const float* Ve2b  = (const float*)d_in[11];
    const float* UdW   = (const float*)d_in[12];
    const float* Udb   = (const float*)d_in[13];
    const float* WdW   = (const float*)d_in[14];
    const float* Vd    = (const float*)d_in[15];
    const float* Vdb   = (const float*)d_in[16];
    const float* e1Wih = (const float*)d_in[17];
    const float* e1Whh = (const float*)d_in[18];
    const float* e1bih = (const float*)d_in[19];
    const float* e1bhh = (const float*)d_in[20];
    const float* e2Wih = (const float*)d_in[21];
    const float* e2Whh = (const float*)d_in[22];
    const float* e2bih = (const float*)d_in[23];
    const float* e2bhh = (const float*)d_in[24];
    const float* dWih  = (const float*)d_in[25];
    const float* dWhh  = (const float*)d_in[26];
    const float* dbih  = (const float*)d_in[27];
    const float* dbhh  = (const float*)d_in[28];
    const float* regW  = (const float*)d_in[29];
    const float* regb  = (const float*)d_in[30];
    float* ws  = (float*)d_ws;
    float* out = (float*)d_out;

    // weights: 417792 halves; biases: 1536 floats
    prep_kernel<<<(417792 + 1536 + 255)/256, 256, 0, stream>>>(
        We1W, We2W, WdW, UdW,
        e1Wih, e1Whh, e1bih, e1bhh,
        e2Wih, e2Whh, e2bih, e2bhh,
        dWih, dWhh, dbih, dbhh, ws);

    const size_t smem = 18596u * sizeof(float);   // 74,384 B -> 2 blocks/CU
    hipFuncSetAttribute((const void*)dstp_main,
                        hipFuncAttributeMaxDynamicSharedMemorySize, (int)smem);
    dstp_main<<<GRID, NTH, smem, stream>>>(
        ipq, labp, Ue1W, Ue1b, Ve1, Ve1b,
        Ue2W, Ue2b, Ve2, Ve2b,
        Udb, Vd, Vdb, regW, regb, ws, out);
}